// Round 1
// baseline (1497.955 us; speedup 1.0000x reference)
//
#include <hip/hip_runtime.h>

#define NPI 50      // nodes per inner graph
#define EPI 400     // edges per inner graph
#define NPO 125     // nodes per outer graph
#define EPO 1000    // edges per outer graph
#define N_OUT 2000
#define NB 16       // batch graphs
#define NC 10

// ---------------------------------------------------------------------------
// Inner section: one workgroup per inner graph (2000 blocks, 256 threads).
// Fuses: degree calc, src-norm, weighted agg, GEMM1+relu, src-norm, agg,
// GEMM2+relu, mean-pool, and the concat with out_layer_feat.
// LDS: 2x 50x128 f32 (25.6KB each) + edges + norms = ~55KB -> 2 blocks/CU.
// ---------------------------------------------------------------------------
__global__ __launch_bounds__(256) void k_inner(
    const float* __restrict__ X, const float* __restrict__ outfeat,
    const float* __restrict__ ew, const int* __restrict__ esrc,
    const int* __restrict__ edst,
    const float* __restrict__ W1, const float* __restrict__ b1,
    const float* __restrict__ W2, const float* __restrict__ b2,
    float* __restrict__ merged)
{
    __shared__ alignas(16) float bufA[NPI * 128];
    __shared__ alignas(16) float bufB[NPI * 128];
    __shared__ float ew_s[EPI];
    __shared__ unsigned short src_s[EPI], dst_s[EPI];
    __shared__ float rs_out[NPI], rs_in[NPI];
    __shared__ int cnt_out[NPI], cnt_in[NPI];

    const int g = blockIdx.x, t = threadIdx.x;
    const int nb = g * NPI, eb = g * EPI;

    for (int i = t; i < NPI; i += 256) { cnt_out[i] = 0; cnt_in[i] = 0; }
    for (int e = t; e < EPI; e += 256) {
        src_s[e] = (unsigned short)(esrc[eb + e] - nb);
        dst_s[e] = (unsigned short)(edst[eb + e] - nb);
        ew_s[e]  = ew[eb + e];
    }
    __syncthreads();
    for (int e = t; e < EPI; e += 256) {
        atomicAdd(&cnt_out[src_s[e]], 1);
        atomicAdd(&cnt_in[dst_s[e]], 1);
    }
    __syncthreads();
    for (int i = t; i < NPI; i += 256) {
        rs_out[i] = rsqrtf((float)max(cnt_out[i], 1));
        rs_in[i]  = rsqrtf((float)max(cnt_in[i], 1));
    }
    __syncthreads();

    // ---- layer 1: load X * rs_out, zero agg (cols 0..63) ----
    for (int idx = t; idx < NPI * 64; idx += 256) {
        int r = idx >> 6, c = idx & 63;
        bufA[r * 128 + c] = X[(nb + r) * 64 + c] * rs_out[r];
        bufB[r * 128 + c] = 0.f;
    }
    __syncthreads();
    // weighted aggregation: wave lanes = feature dim -> conflict-free banks
    for (int idx = t; idx < EPI * 64; idx += 256) {
        int e = idx >> 6, c = idx & 63;
        atomicAdd(&bufB[dst_s[e] * 128 + c], bufA[src_s[e] * 128 + c] * ew_s[e]);
    }
    __syncthreads();
    // GEMM1: h1[r][c] = relu(rs_in[r] * sum_k agg[r][k]*W1[k][c] + b1[c])
    {
        const int c = t & 127, rg = t >> 7;
        float acc[25];
        #pragma unroll
        for (int i = 0; i < 25; i++) acc[i] = 0.f;
        for (int k = 0; k < 64; k += 4) {
            float w0 = W1[(k + 0) * 128 + c], w1 = W1[(k + 1) * 128 + c];
            float w2 = W1[(k + 2) * 128 + c], w3 = W1[(k + 3) * 128 + c];
            #pragma unroll
            for (int i = 0; i < 25; i++) {
                const float4 bv = *(const float4*)&bufB[(rg * 25 + i) * 128 + k];
                acc[i] = fmaf(bv.x, w0, acc[i]); acc[i] = fmaf(bv.y, w1, acc[i]);
                acc[i] = fmaf(bv.z, w2, acc[i]); acc[i] = fmaf(bv.w, w3, acc[i]);
            }
        }
        const float bb = b1[c];
        #pragma unroll
        for (int i = 0; i < 25; i++) {
            int r = rg * 25 + i;
            bufA[r * 128 + c] = fmaxf(fmaf(rs_in[r], acc[i], bb), 0.f);
        }
    }
    __syncthreads();

    // ---- layer 2: scale h1 by rs_out, zero agg (full 128) ----
    for (int idx = t; idx < NPI * 128; idx += 256) {
        int r = idx >> 7;
        bufA[idx] *= rs_out[r];
        bufB[idx] = 0.f;
    }
    __syncthreads();
    for (int idx = t; idx < EPI * 128; idx += 256) {
        int e = idx >> 7, c = idx & 127;
        atomicAdd(&bufB[dst_s[e] * 128 + c], bufA[src_s[e] * 128 + c] * ew_s[e]);
    }
    __syncthreads();
    // GEMM2: K=128
    {
        const int c = t & 127, rg = t >> 7;
        float acc[25];
        #pragma unroll
        for (int i = 0; i < 25; i++) acc[i] = 0.f;
        for (int k = 0; k < 128; k += 4) {
            float w0 = W2[(k + 0) * 128 + c], w1 = W2[(k + 1) * 128 + c];
            float w2 = W2[(k + 2) * 128 + c], w3 = W2[(k + 3) * 128 + c];
            #pragma unroll
            for (int i = 0; i < 25; i++) {
                const float4 bv = *(const float4*)&bufB[(rg * 25 + i) * 128 + k];
                acc[i] = fmaf(bv.x, w0, acc[i]); acc[i] = fmaf(bv.y, w1, acc[i]);
                acc[i] = fmaf(bv.z, w2, acc[i]); acc[i] = fmaf(bv.w, w3, acc[i]);
            }
        }
        const float bb = b2[c];
        #pragma unroll
        for (int i = 0; i < 25; i++) {
            int r = rg * 25 + i;
            bufA[r * 128 + c] = fmaxf(fmaf(rs_in[r], acc[i], bb), 0.f);
        }
    }
    __syncthreads();

    // ---- mean over 50 nodes -> merged[g][64:192]; copy outfeat -> [0:64] ----
    if (t < 128) {
        float s = 0.f;
        for (int r = 0; r < NPI; r++) s += bufA[r * 128 + t];
        merged[g * 192 + 64 + t] = s * (1.f / NPI);
    } else if (t < 192) {
        int c = t - 128;
        merged[g * 192 + c] = outfeat[g * 64 + c];
    }
}

// ---------------------------------------------------------------------------
// Outer degrees (once): 1 block, LDS histogram of 16k edges over 2000 nodes.
// ---------------------------------------------------------------------------
__global__ __launch_bounds__(256) void k_deg_outer(
    const int* __restrict__ src, const int* __restrict__ dst,
    float* __restrict__ rso, float* __restrict__ rsi)
{
    __shared__ int co[N_OUT], ci[N_OUT];
    const int t = threadIdx.x;
    for (int i = t; i < N_OUT; i += 256) { co[i] = 0; ci[i] = 0; }
    __syncthreads();
    for (int e = t; e < NB * EPO; e += 256) {
        atomicAdd(&co[src[e]], 1);
        atomicAdd(&ci[dst[e]], 1);
    }
    __syncthreads();
    for (int i = t; i < N_OUT; i += 256) {
        rso[i] = rsqrtf((float)max(co[i], 1));
        rsi[i] = rsqrtf((float)max(ci[i], 1));
    }
}

// ---------------------------------------------------------------------------
// Outer aggregation: block = (graph, 64-feature chunk). Gathers x from global
// (L2-resident, <=1.5MB), LDS-atomic accumulate, writes rs_in-scaled agg.
// ---------------------------------------------------------------------------
template <int FIN>
__global__ __launch_bounds__(256) void k_agg_outer(
    const float* __restrict__ x, const float* __restrict__ ew,
    const int* __restrict__ esrc, const int* __restrict__ edst,
    const float* __restrict__ rso, const float* __restrict__ rsi,
    float* __restrict__ out)
{
    __shared__ float agg[NPO * 64];
    __shared__ float ew_s[EPO];
    __shared__ unsigned short src_s[EPO], dst_s[EPO];
    __shared__ float rso_s[NPO], rsi_s[NPO];
    constexpr int NKC = FIN / 64;
    const int g = blockIdx.x / NKC, kc = blockIdx.x % NKC;
    const int t = threadIdx.x, nb = g * NPO, eb = g * EPO;

    for (int e = t; e < EPO; e += 256) {
        src_s[e] = (unsigned short)(esrc[eb + e] - nb);
        dst_s[e] = (unsigned short)(edst[eb + e] - nb);
        ew_s[e]  = ew[eb + e];
    }
    for (int i = t; i < NPO; i += 256) { rso_s[i] = rso[nb + i]; rsi_s[i] = rsi[nb + i]; }
    for (int i = t; i < NPO * 64; i += 256) agg[i] = 0.f;
    __syncthreads();
    for (int idx = t; idx < EPO * 64; idx += 256) {
        int e = idx >> 6, c = idx & 63;
        int s = src_s[e];
        float v = x[(nb + s) * FIN + kc * 64 + c] * rso_s[s] * ew_s[e];
        atomicAdd(&agg[dst_s[e] * 64 + c], v);
    }
    __syncthreads();
    for (int idx = t; idx < NPO * 64; idx += 256) {
        int r = idx >> 6, c = idx & 63;
        out[(nb + r) * FIN + kc * 64 + c] = agg[idx] * rsi_s[r];
    }
}

// ---------------------------------------------------------------------------
// Outer GEMM: [2000 x K] @ [K x 128] + bias, relu. 40 blocks of 50 rows.
// ---------------------------------------------------------------------------
template <int K>
__global__ __launch_bounds__(256) void k_gemm_outer(
    const float* __restrict__ in, const float* __restrict__ W,
    const float* __restrict__ bias, float* __restrict__ out)
{
    __shared__ alignas(16) float tile[50 * K];
    const int b = blockIdx.x, t = threadIdx.x;
    const int row0 = b * 50;
    for (int idx = t; idx < 50 * K; idx += 256) tile[idx] = in[row0 * K + idx];
    __syncthreads();
    const int c = t & 127, rg = t >> 7;
    float acc[25];
    #pragma unroll
    for (int i = 0; i < 25; i++) acc[i] = 0.f;
    for (int k = 0; k < K; k += 4) {
        float w0 = W[(k + 0) * 128 + c], w1 = W[(k + 1) * 128 + c];
        float w2 = W[(k + 2) * 128 + c], w3 = W[(k + 3) * 128 + c];
        #pragma unroll
        for (int i = 0; i < 25; i++) {
            const float4 bv = *(const float4*)&tile[(rg * 25 + i) * K + k];
            acc[i] = fmaf(bv.x, w0, acc[i]); acc[i] = fmaf(bv.y, w1, acc[i]);
            acc[i] = fmaf(bv.z, w2, acc[i]); acc[i] = fmaf(bv.w, w3, acc[i]);
        }
    }
    const float bb = bias[c];
    #pragma unroll
    for (int i = 0; i < 25; i++)
        out[(row0 + rg * 25 + i) * 128 + c] = fmaxf(acc[i] + bb, 0.f);
}

// ---------------------------------------------------------------------------
// Readout: mean over 125 nodes per batch graph, then [16x128] @ [128x10] + bc.
// ---------------------------------------------------------------------------
__global__ __launch_bounds__(128) void k_final(
    const float* __restrict__ h, const float* __restrict__ Wc,
    const float* __restrict__ bc, float* __restrict__ out)
{
    __shared__ float hg[128];
    const int g = blockIdx.x, t = threadIdx.x;
    float s = 0.f;
    for (int r = 0; r < NPO; r++) s += h[(g * NPO + r) * 128 + t];
    hg[t] = s * (1.f / NPO);
    __syncthreads();
    if (t < NC) {
        float acc = bc[t];
        for (int k = 0; k < 128; k++) acc = fmaf(hg[k], Wc[k * NC + t], acc);
        out[g * NC + t] = acc;
    }
}

extern "C" void kernel_launch(void* const* d_in, const int* in_sizes, int n_in,
                              void* d_out, int out_size, void* d_ws, size_t ws_size,
                              hipStream_t stream)
{
    const float* X       = (const float*)d_in[0];
    const float* outfeat = (const float*)d_in[1];
    const float* iew     = (const float*)d_in[2];
    const float* oew     = (const float*)d_in[3];
    const float* W1 = (const float*)d_in[4];  const float* b1 = (const float*)d_in[5];
    const float* W2 = (const float*)d_in[6];  const float* b2 = (const float*)d_in[7];
    const float* W3 = (const float*)d_in[8];  const float* b3 = (const float*)d_in[9];
    const float* W4 = (const float*)d_in[10]; const float* b4 = (const float*)d_in[11];
    const float* W5 = (const float*)d_in[12]; const float* b5 = (const float*)d_in[13];
    const float* W6 = (const float*)d_in[14]; const float* b6 = (const float*)d_in[15];
    const float* Wc = (const float*)d_in[16]; const float* bc = (const float*)d_in[17];
    const int* isrc = (const int*)d_in[18];   const int* idst = (const int*)d_in[19];
    const int* osrc = (const int*)d_in[20];   const int* odst = (const int*)d_in[21];

    float* ws     = (float*)d_ws;
    float* merged = ws;               // 2000*192 = 384000
    float* aggbuf = ws + 384000;      // 2000*192 = 384000
    float* h1     = ws + 768000;      // 2000*128 = 256000
    float* h2     = ws + 1024000;     // 2000*128 = 256000
    float* rso    = ws + 1280000;     // 2000
    float* rsi    = ws + 1282000;     // 2000

    k_inner<<<N_OUT, 256, 0, stream>>>(X, outfeat, iew, isrc, idst, W1, b1, W2, b2, merged);
    k_deg_outer<<<1, 256, 0, stream>>>(osrc, odst, rso, rsi);

    k_agg_outer<192><<<NB * 3, 256, 0, stream>>>(merged, oew, osrc, odst, rso, rsi, aggbuf);
    k_gemm_outer<192><<<40, 256, 0, stream>>>(aggbuf, W3, b3, h1);

    k_agg_outer<128><<<NB * 2, 256, 0, stream>>>(h1, oew, osrc, odst, rso, rsi, aggbuf);
    k_gemm_outer<128><<<40, 256, 0, stream>>>(aggbuf, W4, b4, h2);

    k_agg_outer<128><<<NB * 2, 256, 0, stream>>>(h2, oew, osrc, odst, rso, rsi, aggbuf);
    k_gemm_outer<128><<<40, 256, 0, stream>>>(aggbuf, W5, b5, h1);

    k_agg_outer<128><<<NB * 2, 256, 0, stream>>>(h1, oew, osrc, odst, rso, rsi, aggbuf);
    k_gemm_outer<128><<<40, 256, 0, stream>>>(aggbuf, W6, b6, h2);

    k_final<<<NB, 128, 0, stream>>>(h2, Wc, bc, (float*)d_out);
}

// Round 2
// 1377.019 us; speedup vs baseline: 1.0878x; 1.0878x over previous
//
#include <hip/hip_runtime.h>

#define NPI 50      // nodes per inner graph
#define EPI 400     // edges per inner graph
#define NPO 125     // nodes per outer graph
#define EPO 1000    // edges per outer graph
#define N_IN 100000
#define N_OUT 2000
#define NB 16       // batch graphs
#define NC 10

typedef _Float16 half_t;
typedef _Float16 f16x8 __attribute__((ext_vector_type(8)));
typedef float f32x4 __attribute__((ext_vector_type(4)));

// ---------------------------------------------------------------------------
// Prep: convert W1..W6 (f32, [K][128]) to transposed f16 WT ([128][K]).
// 98304 total elements, grid 384 x 256.
// ---------------------------------------------------------------------------
__global__ __launch_bounds__(256) void k_prep(
    const float* __restrict__ W1, const float* __restrict__ W2,
    const float* __restrict__ W3, const float* __restrict__ W4,
    const float* __restrict__ W5, const float* __restrict__ W6,
    half_t* __restrict__ WT1, half_t* __restrict__ WT2,
    half_t* __restrict__ WT3, half_t* __restrict__ WT4,
    half_t* __restrict__ WT5, half_t* __restrict__ WT6)
{
    int i = blockIdx.x * 256 + threadIdx.x;
    const float* src; half_t* dst; int K;
    if      (i < 8192)  { src = W1; dst = WT1; K = 64; }
    else if (i < 24576) { src = W2; dst = WT2; K = 128; i -= 8192; }
    else if (i < 49152) { src = W3; dst = WT3; K = 192; i -= 24576; }
    else if (i < 65536) { src = W4; dst = WT4; K = 128; i -= 49152; }
    else if (i < 81920) { src = W5; dst = WT5; K = 128; i -= 65536; }
    else                { src = W6; dst = WT6; K = 128; i -= 81920; }
    int c = i & 127, k = i >> 7;
    dst[c * K + k] = (half_t)src[k * 128 + c];
}

// ---------------------------------------------------------------------------
// MFMA GEMM: out[r][c] = post( rs_in[r]*sum_k A[r][k]*WT[c][k] + bias[c] )
// post = relu, then optionally *rs_out[r] (pre-scales next layer's gather).
// A: [M][K] f16 row-major.  WT: [128][K] f16.  out: [M][128] f16.
// Block = 256 thr = 4 waves; wave = 32 rows x 128 cols (2x8 16x16 tiles).
// A-frag (16x16x32): lane l holds A[l%16][8*(l/16)+j]; B-frag: WT[c=l%16][...].
// C/D: col = l&15, row = (l>>4)*4 + reg  [verified m89].
// ---------------------------------------------------------------------------
template <int K, bool SCALE>
__global__ __launch_bounds__(256) void k_gemm(
    const half_t* __restrict__ A, const half_t* __restrict__ BT,
    const float* __restrict__ bias, const float* __restrict__ rs_in,
    const float* __restrict__ rs_out, half_t* __restrict__ out, int M)
{
    const int t = threadIdx.x, w = t >> 6, l = t & 63;
    const int lr = l & 15, lk = l >> 4;
    const int r0 = blockIdx.x * 128 + w * 32;

    f32x4 acc[2][8] = {};
    const int ra = (r0 + lr      < M) ? (r0 + lr)      : (M - 1);
    const int rb = (r0 + 16 + lr < M) ? (r0 + 16 + lr) : (M - 1);

    for (int ks = 0; ks < K / 32; ks++) {
        const int ko = ks * 32 + lk * 8;
        f16x8 a0 = *(const f16x8*)&A[(size_t)ra * K + ko];
        f16x8 a1 = *(const f16x8*)&A[(size_t)rb * K + ko];
        #pragma unroll
        for (int ct = 0; ct < 8; ct++) {
            f16x8 b = *(const f16x8*)&BT[(size_t)(ct * 16 + lr) * K + ko];
            acc[0][ct] = __builtin_amdgcn_mfma_f32_16x16x32_f16(a0, b, acc[0][ct], 0, 0, 0);
            acc[1][ct] = __builtin_amdgcn_mfma_f32_16x16x32_f16(a1, b, acc[1][ct], 0, 0, 0);
        }
    }

    #pragma unroll
    for (int rt = 0; rt < 2; rt++) {
        #pragma unroll
        for (int q = 0; q < 4; q++) {
            int r = r0 + rt * 16 + lk * 4 + q;
            if (r < M) {
                float ri = rs_in[r];
                float ro = SCALE ? rs_out[r] : 1.f;
                #pragma unroll
                for (int ct = 0; ct < 8; ct++) {
                    int c = ct * 16 + lr;
                    float v = fmaxf(fmaf(acc[rt][ct][q], ri, bias[c]), 0.f);
                    out[(size_t)r * 128 + c] = (half_t)(v * ro);
                }
            }
        }
    }
}

// ---------------------------------------------------------------------------
// Inner aggregation, layer 1: per-graph block. Computes degrees (writes
// rs_in/rs_out arrays for the GEMM epilogues), stages xs = X*rs_out in LDS,
// LDS-atomic weighted scatter, writes agg (f16, un-normalized).
// ---------------------------------------------------------------------------
__global__ __launch_bounds__(256) void k_agg_in1(
    const float* __restrict__ X, const float* __restrict__ ew,
    const int* __restrict__ esrc, const int* __restrict__ edst,
    half_t* __restrict__ aggo, float* __restrict__ rs_in_g,
    float* __restrict__ rs_out_g)
{
    __shared__ float xs[NPI * 64];
    __shared__ float agg[NPI * 64];
    __shared__ float ew_s[EPI];
    __shared__ unsigned short src_s[EPI], dst_s[EPI];
    __shared__ float rs_out[NPI];
    __shared__ int cnt_o[NPI], cnt_i[NPI];

    const int g = blockIdx.x, t = threadIdx.x, nb = g * NPI, eb = g * EPI;
    for (int i = t; i < NPI; i += 256) { cnt_o[i] = 0; cnt_i[i] = 0; }
    for (int e = t; e < EPI; e += 256) {
        src_s[e] = (unsigned short)(esrc[eb + e] - nb);
        dst_s[e] = (unsigned short)(edst[eb + e] - nb);
        ew_s[e]  = ew[eb + e];
    }
    __syncthreads();
    for (int e = t; e < EPI; e += 256) {
        atomicAdd(&cnt_o[src_s[e]], 1);
        atomicAdd(&cnt_i[dst_s[e]], 1);
    }
    __syncthreads();
    for (int i = t; i < NPI; i += 256) {
        float ro = rsqrtf((float)max(cnt_o[i], 1));
        float ri = rsqrtf((float)max(cnt_i[i], 1));
        rs_out[i] = ro; rs_out_g[nb + i] = ro; rs_in_g[nb + i] = ri;
    }
    __syncthreads();
    for (int idx = t; idx < NPI * 64; idx += 256) {
        int r = idx >> 6;
        xs[idx] = X[(size_t)(nb + r) * 64 + (idx & 63)] * rs_out[r];
        agg[idx] = 0.f;
    }
    __syncthreads();
    for (int idx = t; idx < EPI * 64; idx += 256) {
        int e = idx >> 6, c = idx & 63;
        atomicAdd(&agg[dst_s[e] * 64 + c], xs[src_s[e] * 64 + c] * ew_s[e]);
    }
    __syncthreads();
    for (int idx = t; idx < NPI * 64; idx += 256)
        aggo[(size_t)nb * 64 + idx] = (half_t)agg[idx];
}

// ---------------------------------------------------------------------------
// Inner aggregation, layer 2: input h1s (f16, already *rs_out), 128 feats.
// ---------------------------------------------------------------------------
__global__ __launch_bounds__(256) void k_agg_in2(
    const half_t* __restrict__ h1s, const float* __restrict__ ew,
    const int* __restrict__ esrc, const int* __restrict__ edst,
    half_t* __restrict__ aggo)
{
    __shared__ alignas(16) half_t xs[NPI * 128];
    __shared__ float agg[NPI * 128];
    __shared__ float ew_s[EPI];
    __shared__ unsigned short src_s[EPI], dst_s[EPI];

    const int g = blockIdx.x, t = threadIdx.x, nb = g * NPI, eb = g * EPI;
    for (int e = t; e < EPI; e += 256) {
        src_s[e] = (unsigned short)(esrc[eb + e] - nb);
        dst_s[e] = (unsigned short)(edst[eb + e] - nb);
        ew_s[e]  = ew[eb + e];
    }
    // vectorized LDS stage of 50x128 f16 (8 halfs per thread-iter)
    for (int idx = t; idx < NPI * 16; idx += 256)
        *(int4*)&xs[idx * 8] = *(const int4*)&h1s[(size_t)nb * 128 + idx * 8];
    for (int idx = t; idx < NPI * 128; idx += 256) agg[idx] = 0.f;
    __syncthreads();
    for (int idx = t; idx < EPI * 128; idx += 256) {
        int e = idx >> 7, c = idx & 127;
        atomicAdd(&agg[dst_s[e] * 128 + c], (float)xs[src_s[e] * 128 + c] * ew_s[e]);
    }
    __syncthreads();
    for (int idx = t; idx < NPI * 128; idx += 256)
        aggo[(size_t)nb * 128 + idx] = (half_t)agg[idx];
}

// ---------------------------------------------------------------------------
// Outer degrees (once): writes rso/rsi [2000].
// ---------------------------------------------------------------------------
__global__ __launch_bounds__(256) void k_deg_outer(
    const int* __restrict__ src, const int* __restrict__ dst,
    float* __restrict__ rso, float* __restrict__ rsi)
{
    __shared__ int co[N_OUT], ci[N_OUT];
    const int t = threadIdx.x;
    for (int i = t; i < N_OUT; i += 256) { co[i] = 0; ci[i] = 0; }
    __syncthreads();
    for (int e = t; e < NB * EPO; e += 256) {
        atomicAdd(&co[src[e]], 1);
        atomicAdd(&ci[dst[e]], 1);
    }
    __syncthreads();
    for (int i = t; i < N_OUT; i += 256) {
        rso[i] = rsqrtf((float)max(co[i], 1));
        rsi[i] = rsqrtf((float)max(ci[i], 1));
    }
}

// ---------------------------------------------------------------------------
// Outer aggregation: block = (graph, 64-col chunk); input already *rs_out.
// ---------------------------------------------------------------------------
template <int FIN>
__global__ __launch_bounds__(256) void k_agg_out(
    const half_t* __restrict__ x, const float* __restrict__ ew,
    const int* __restrict__ esrc, const int* __restrict__ edst,
    half_t* __restrict__ out)
{
    __shared__ half_t xs[NPO * 64];
    __shared__ float agg[NPO * 64];
    __shared__ float ew_s[EPO];
    __shared__ unsigned short src_s[EPO], dst_s[EPO];
    constexpr int NKC = FIN / 64;
    const int g = blockIdx.x / NKC, kc = blockIdx.x % NKC;
    const int t = threadIdx.x, nb = g * NPO, eb = g * EPO;

    for (int e = t; e < EPO; e += 256) {
        src_s[e] = (unsigned short)(esrc[eb + e] - nb);
        dst_s[e] = (unsigned short)(edst[eb + e] - nb);
        ew_s[e]  = ew[eb + e];
    }
    for (int i = t; i < NPO * 64; i += 256) {
        xs[i] = x[(size_t)(nb + (i >> 6)) * FIN + kc * 64 + (i & 63)];
        agg[i] = 0.f;
    }
    __syncthreads();
    for (int idx = t; idx < EPO * 64; idx += 256) {
        int e = idx >> 6, c = idx & 63;
        atomicAdd(&agg[dst_s[e] * 64 + c], (float)xs[src_s[e] * 64 + c] * ew_s[e]);
    }
    __syncthreads();
    for (int i = t; i < NPO * 64; i += 256)
        out[(size_t)(nb + (i >> 6)) * FIN + kc * 64 + (i & 63)] = (half_t)agg[i];
}

// ---------------------------------------------------------------------------
// Pool inner h2 (mean over 50 nodes), concat with outfeat, pre-scale by rso.
// merged_s: [2000][192] f16 = rso[g] * concat(outfeat, mean(h2)).
// ---------------------------------------------------------------------------
__global__ __launch_bounds__(256) void k_pool_merge(
    const half_t* __restrict__ h2, const float* __restrict__ outfeat,
    const float* __restrict__ rso, half_t* __restrict__ merged_s)
{
    const int g = blockIdx.x, t = threadIdx.x;
    const float ro = rso[g];
    if (t < 64) {
        merged_s[(size_t)g * 192 + t] = (half_t)(outfeat[(size_t)g * 64 + t] * ro);
    } else if (t < 192) {
        int c = t - 64;
        float s = 0.f;
        for (int r = 0; r < NPI; r++) s += (float)h2[((size_t)g * NPI + r) * 128 + c];
        merged_s[(size_t)g * 192 + t] = (half_t)(s * (1.f / NPI) * ro);
    }
}

// ---------------------------------------------------------------------------
// Readout: mean over 125 nodes, then [16x128] @ Wc[128x10] + bc (f32).
// ---------------------------------------------------------------------------
__global__ __launch_bounds__(128) void k_final(
    const half_t* __restrict__ h6, const float* __restrict__ Wc,
    const float* __restrict__ bc, float* __restrict__ out)
{
    __shared__ float hg[128];
    const int g = blockIdx.x, t = threadIdx.x;
    float s = 0.f;
    for (int r = 0; r < NPO; r++) s += (float)h6[((size_t)g * NPO + r) * 128 + t];
    hg[t] = s * (1.f / NPO);
    __syncthreads();
    if (t < NC) {
        float acc = bc[t];
        for (int k = 0; k < 128; k++) acc = fmaf(hg[k], Wc[k * NC + t], acc);
        out[g * NC + t] = acc;
    }
}

extern "C" void kernel_launch(void* const* d_in, const int* in_sizes, int n_in,
                              void* d_out, int out_size, void* d_ws, size_t ws_size,
                              hipStream_t stream)
{
    const float* X       = (const float*)d_in[0];
    const float* outfeat = (const float*)d_in[1];
    const float* iew     = (const float*)d_in[2];
    const float* oew     = (const float*)d_in[3];
    const float* W1 = (const float*)d_in[4];  const float* b1 = (const float*)d_in[5];
    const float* W2 = (const float*)d_in[6];  const float* b2 = (const float*)d_in[7];
    const float* W3 = (const float*)d_in[8];  const float* b3 = (const float*)d_in[9];
    const float* W4 = (const float*)d_in[10]; const float* b4 = (const float*)d_in[11];
    const float* W5 = (const float*)d_in[12]; const float* b5 = (const float*)d_in[13];
    const float* W6 = (const float*)d_in[14]; const float* b6 = (const float*)d_in[15];
    const float* Wc = (const float*)d_in[16]; const float* bc = (const float*)d_in[17];
    const int* isrc = (const int*)d_in[18];   const int* idst = (const int*)d_in[19];
    const int* osrc = (const int*)d_in[20];   const int* odst = (const int*)d_in[21];

    char* base = (char*)d_ws;
    // WT buffers (f16): sizes 8192,16384,24576,16384,16384,16384 halfs
    half_t* WT1 = (half_t*)(base + 0);
    half_t* WT2 = (half_t*)(base + 16384);
    half_t* WT3 = (half_t*)(base + 49152);
    half_t* WT4 = (half_t*)(base + 98304);
    half_t* WT5 = (half_t*)(base + 131072);
    half_t* WT6 = (half_t*)(base + 163840);
    float* rs_in  = (float*)(base + 196608);   // [100000]
    float* rs_out = (float*)(base + 596608);   // [100000]
    float* rso    = (float*)(base + 996608);   // [2000]
    float* rsi    = (float*)(base + 1004608);  // [2000]
    half_t* merged_s = (half_t*)(base + 1012608); // [2000][192]
    half_t* aggO     = (half_t*)(base + 1780608); // [2000][192] (reused at 128)
    half_t* hO       = (half_t*)(base + 2548608); // [2000][128]
    half_t* bufA     = (half_t*)(base + 3060608); // [100000][128]
    half_t* bufB     = (half_t*)(base + 28660608);// [100000][128]

    k_prep<<<384, 256, 0, stream>>>(W1, W2, W3, W4, W5, W6, WT1, WT2, WT3, WT4, WT5, WT6);
    k_deg_outer<<<1, 256, 0, stream>>>(osrc, odst, rso, rsi);

    // ---- inner section ----
    k_agg_in1<<<N_OUT, 256, 0, stream>>>(X, iew, isrc, idst, bufA, rs_in, rs_out);
    k_gemm<64, true><<<(N_IN + 127) / 128, 256, 0, stream>>>(
        bufA, WT1, b1, rs_in, rs_out, bufB, N_IN);              // h1s (scaled)
    k_agg_in2<<<N_OUT, 256, 0, stream>>>(bufB, iew, isrc, idst, bufA);
    k_gemm<128, false><<<(N_IN + 127) / 128, 256, 0, stream>>>(
        bufA, WT2, b2, rs_in, rs_out, bufB, N_IN);              // h2 (plain)
    k_pool_merge<<<N_OUT, 256, 0, stream>>>(bufB, outfeat, rso, merged_s);

    // ---- outer section ----
    k_agg_out<192><<<NB * 3, 256, 0, stream>>>(merged_s, oew, osrc, odst, aggO);
    k_gemm<192, true><<<16, 256, 0, stream>>>(aggO, WT3, b3, rsi, rso, hO, N_OUT);
    k_agg_out<128><<<NB * 2, 256, 0, stream>>>(hO, oew, osrc, odst, aggO);
    k_gemm<128, true><<<16, 256, 0, stream>>>(aggO, WT4, b4, rsi, rso, hO, N_OUT);
    k_agg_out<128><<<NB * 2, 256, 0, stream>>>(hO, oew, osrc, odst, aggO);
    k_gemm<128, true><<<16, 256, 0, stream>>>(aggO, WT5, b5, rsi, rso, hO, N_OUT);
    k_agg_out<128><<<NB * 2, 256, 0, stream>>>(hO, oew, osrc, odst, aggO);
    k_gemm<128, false><<<16, 256, 0, stream>>>(aggO, WT6, b6, rsi, rso, hO, N_OUT);

    k_final<<<NB, 128, 0, stream>>>(hO, Wc, bc, (float*)d_out);
}

// Round 3
// 141.735 us; speedup vs baseline: 10.5687x; 9.7154x over previous
//
#include <hip/hip_runtime.h>

#define NPI 50      // nodes per inner graph
#define EPI 400     // edges per inner graph
#define NPO 125     // nodes per outer graph
#define EPO 1000    // edges per outer graph
#define N_IN 100000
#define N_OUT 2000
#define NB 16       // batch graphs
#define NC 10

typedef _Float16 half_t;
typedef _Float16 f16x8 __attribute__((ext_vector_type(8)));
typedef float f32x4 __attribute__((ext_vector_type(4)));

#define MFMA(a, b, c) __builtin_amdgcn_mfma_f32_16x16x32_f16(a, b, c, 0, 0, 0)

// Swizzled LDS access for row-major f16 tiles (stride multiple of 128B).
// XOR of (row&7) into byte-bits 4..6 keeps ds_read_b128 conflict-free when
// 16 lanes read 16 consecutive rows at the same column offset.
__device__ __forceinline__ f16x8 lds_ldA(const half_t* base, int row, int kelem, int strideB) {
    return *(const f16x8*)((const char*)base + row * strideB + ((kelem * 2) ^ ((row & 7) << 4)));
}
__device__ __forceinline__ void lds_st(half_t* base, int row, int col, int strideB, float v) {
    *(half_t*)((char*)base + row * strideB + ((col * 2) ^ ((row & 7) << 4))) = (half_t)v;
}
__device__ __forceinline__ void lds_sth(half_t* base, int row, int col, int strideB, half_t v) {
    *(half_t*)((char*)base + row * strideB + ((col * 2) ^ ((row & 7) << 4))) = v;
}

// ---------------------------------------------------------------------------
// Prep: W1..W6 (f32, [K][128]) -> transposed f16 WT ([128][K]).
// ---------------------------------------------------------------------------
__global__ __launch_bounds__(256) void k_prep(
    const float* __restrict__ W1, const float* __restrict__ W2,
    const float* __restrict__ W3, const float* __restrict__ W4,
    const float* __restrict__ W5, const float* __restrict__ W6,
    half_t* __restrict__ WT1, half_t* __restrict__ WT2,
    half_t* __restrict__ WT3, half_t* __restrict__ WT4,
    half_t* __restrict__ WT5, half_t* __restrict__ WT6)
{
    int i = blockIdx.x * 256 + threadIdx.x;
    const float* src; half_t* dst; int K;
    if      (i < 8192)  { src = W1; dst = WT1; K = 64; }
    else if (i < 24576) { src = W2; dst = WT2; K = 128; i -= 8192; }
    else if (i < 49152) { src = W3; dst = WT3; K = 192; i -= 24576; }
    else if (i < 65536) { src = W4; dst = WT4; K = 128; i -= 49152; }
    else if (i < 81920) { src = W5; dst = WT5; K = 128; i -= 65536; }
    else                { src = W6; dst = WT6; K = 128; i -= 81920; }
    int c = i & 127, k = i >> 7;
    dst[c * K + k] = (half_t)src[k * 128 + c];
}

// ---------------------------------------------------------------------------
// Inner fused: per-graph dense-adjacency MFMA pipeline.
// Â[d][s] = rs_in[d] * sum(ew s->d) * rs_out[s]   (zero-padded to 64x64)
// h1 = relu((Â@X)@W1+b1); h2 = relu((Â@h1)@W2+b2); merged = [outfeat, mean(h2)]
// ---------------------------------------------------------------------------
__global__ __launch_bounds__(256) void k_inner_fused(
    const float* __restrict__ X, const float* __restrict__ outfeat,
    const float* __restrict__ ew, const int* __restrict__ esrc,
    const int* __restrict__ edst,
    const half_t* __restrict__ WT1, const float* __restrict__ b1,
    const half_t* __restrict__ WT2, const float* __restrict__ b2,
    half_t* __restrict__ merged)
{
    __shared__ alignas(16) char smem[42496];
    half_t* Ah   = (half_t*)smem;              // [64][64] swz, 8KB
    half_t* bufP = (half_t*)(smem + 8192);     // [128][64] swz, 16KB (XT then h1T)
    half_t* bufQ = (half_t*)(smem + 24576);    // [64][128] swz, 16KB (T1/T2), aliases Af
    float*  Af   = (float*)(smem + 24576);     // [50][64] f32 build buffer
    float*  pool = (float*)(smem + 40960);     // [128]
    float*  rsoS = (float*)(smem + 41472);     // [64]
    float*  rsiS = (float*)(smem + 41728);     // [64]
    int*    cO   = (int*)(smem + 41984);       // [64]
    int*    cI   = (int*)(smem + 42240);       // [64]

    const int g = blockIdx.x, t = threadIdx.x;
    const int w = t >> 6, l = t & 63, lr = l & 15, lk = l >> 4;
    const int nb = g * NPI, eb = g * EPI;

    if (t < 64) { cO[t] = 0; cI[t] = 0; }
    if (t >= 64 && t < 192) pool[t - 64] = 0.f;
    for (int i = t; i < NPI * 64; i += 256) Af[i] = 0.f;
    __syncthreads();
    for (int e = t; e < EPI; e += 256) {
        int s = esrc[eb + e] - nb, d = edst[eb + e] - nb;
        atomicAdd(&Af[d * 64 + s], ew[eb + e]);
        atomicAdd(&cO[s], 1); atomicAdd(&cI[d], 1);
    }
    __syncthreads();
    if (t < 64) {
        rsoS[t] = rsqrtf((float)max(cO[t], 1));
        rsiS[t] = rsqrtf((float)max(cI[t], 1));
    }
    __syncthreads();
    // Â -> f16 swizzled; X^T -> bufP rows 0..63 (feat-major), zero-padded
    for (int i = t; i < 64 * 64; i += 256) {
        int d = i >> 6, s = i & 63;
        float v = (d < NPI && s < NPI) ? Af[d * 64 + s] * rsiS[d] * rsoS[s] : 0.f;
        lds_st(Ah, d, s, 128, v);
    }
    for (int i = t; i < 64 * 64; i += 256) {
        int s = i >> 6, f = i & 63;
        float v = (s < NPI) ? X[(size_t)(nb + s) * 64 + f] : 0.f;
        lds_st(bufP, f, s, 128, v);
    }
    __syncthreads();

    // T1 = Â @ X : M=64(16/wave), N=64, K=64 -> bufQ
    {
        f32x4 acc[4] = {};
        const int ar = w * 16 + lr;
        #pragma unroll
        for (int ks = 0; ks < 2; ks++) {
            f16x8 a = lds_ldA(Ah, ar, ks * 32 + lk * 8, 128);
            #pragma unroll
            for (int nt = 0; nt < 4; nt++) {
                f16x8 b = lds_ldA(bufP, nt * 16 + lr, ks * 32 + lk * 8, 128);
                acc[nt] = MFMA(a, b, acc[nt]);
            }
        }
        #pragma unroll
        for (int nt = 0; nt < 4; nt++)
            #pragma unroll
            for (int q = 0; q < 4; q++)
                lds_st(bufQ, w * 16 + lk * 4 + q, nt * 16 + lr, 256, acc[nt][q]);
    }
    __syncthreads();   // all T1 reads of bufP done before h1T overwrites it

    // H1 = relu(T1 @ W1 + b1) -> bufP transposed [f][d]
    {
        f32x4 acc[8] = {};
        const int ar = w * 16 + lr;
        #pragma unroll
        for (int ks = 0; ks < 2; ks++) {
            f16x8 a = lds_ldA(bufQ, ar, ks * 32 + lk * 8, 256);
            #pragma unroll
            for (int nt = 0; nt < 8; nt++) {
                f16x8 b = *(const f16x8*)&WT1[(nt * 16 + lr) * 64 + ks * 32 + lk * 8];
                acc[nt] = MFMA(a, b, acc[nt]);
            }
        }
        #pragma unroll
        for (int nt = 0; nt < 8; nt++) {
            int f = nt * 16 + lr;
            float bb = b1[f];
            #pragma unroll
            for (int q = 0; q < 4; q++)
                lds_st(bufP, f, w * 16 + lk * 4 + q, 128, fmaxf(acc[nt][q] + bb, 0.f));
        }
    }
    __syncthreads();

    // T2 = Â @ h1 -> bufQ (wave-private rows)
    {
        f32x4 acc[8] = {};
        const int ar = w * 16 + lr;
        #pragma unroll
        for (int ks = 0; ks < 2; ks++) {
            f16x8 a = lds_ldA(Ah, ar, ks * 32 + lk * 8, 128);
            #pragma unroll
            for (int nt = 0; nt < 8; nt++) {
                f16x8 b = lds_ldA(bufP, nt * 16 + lr, ks * 32 + lk * 8, 128);
                acc[nt] = MFMA(a, b, acc[nt]);
            }
        }
        #pragma unroll
        for (int nt = 0; nt < 8; nt++)
            #pragma unroll
            for (int q = 0; q < 4; q++)
                lds_st(bufQ, w * 16 + lk * 4 + q, nt * 16 + lr, 256, acc[nt][q]);
    }
    // bufQ is wave-private -> no barrier needed

    // H2 = relu(T2 @ W2 + b2), masked column-sum -> pool
    {
        f32x4 acc[8] = {};
        const int ar = w * 16 + lr;
        #pragma unroll
        for (int ks = 0; ks < 4; ks++) {
            f16x8 a = lds_ldA(bufQ, ar, ks * 32 + lk * 8, 256);
            #pragma unroll
            for (int nt = 0; nt < 8; nt++) {
                f16x8 b = *(const f16x8*)&WT2[(nt * 16 + lr) * 128 + ks * 32 + lk * 8];
                acc[nt] = MFMA(a, b, acc[nt]);
            }
        }
        #pragma unroll
        for (int nt = 0; nt < 8; nt++) {
            int f = nt * 16 + lr;
            float bb = b2[f];
            float ps = 0.f;
            #pragma unroll
            for (int q = 0; q < 4; q++) {
                int d = w * 16 + lk * 4 + q;
                float v = fmaxf(acc[nt][q] + bb, 0.f);
                ps += (d < NPI) ? v : 0.f;
            }
            ps += __shfl_xor(ps, 16);
            ps += __shfl_xor(ps, 32);
            if (lk == 0) atomicAdd(&pool[f], ps);
        }
    }
    __syncthreads();
    if (t < 64) merged[(size_t)g * 192 + t] = (half_t)outfeat[(size_t)g * 64 + t];
    else if (t < 192) merged[(size_t)g * 192 + t] = (half_t)(pool[t - 64] * (1.f / NPI));
}

// ---------------------------------------------------------------------------
// Outer adjacency build: dense Â_outer [16][128][128] f16 to global.
// ---------------------------------------------------------------------------
__global__ __launch_bounds__(256) void k_adj_out(
    const float* __restrict__ ew, const int* __restrict__ esrc,
    const int* __restrict__ edst, half_t* __restrict__ Aout)
{
    __shared__ float Af[NPO * NPO];
    __shared__ int cO[NPO], cI[NPO];
    __shared__ float rso[NPO], rsi[NPO];
    const int g = blockIdx.x, t = threadIdx.x;
    const int nb = g * NPO, eb = g * EPO;
    for (int i = t; i < NPO * NPO; i += 256) Af[i] = 0.f;
    if (t < NPO) { cO[t] = 0; cI[t] = 0; }
    __syncthreads();
    for (int e = t; e < EPO; e += 256) {
        int s = esrc[eb + e] - nb, d = edst[eb + e] - nb;
        atomicAdd(&Af[d * NPO + s], ew[eb + e]);
        atomicAdd(&cO[s], 1); atomicAdd(&cI[d], 1);
    }
    __syncthreads();
    if (t < NPO) {
        rso[t] = rsqrtf((float)max(cO[t], 1));
        rsi[t] = rsqrtf((float)max(cI[t], 1));
    }
    __syncthreads();
    for (int i = t; i < 128 * 16; i += 256) {
        int d = i >> 4, s0 = (i & 15) * 8;
        f16x8 v;
        #pragma unroll
        for (int j = 0; j < 8; j++) {
            int s = s0 + j;
            float x = (d < NPO && s < NPO) ? Af[d * NPO + s] * rsi[d] * rso[s] : 0.f;
            v[j] = (half_t)x;
        }
        *(f16x8*)&Aout[(size_t)g * 16384 + d * 128 + s0] = v;
    }
}

// ---------------------------------------------------------------------------
// Outer fused layer: hacc = relu((Â@h_in)@W + b), chunked over h_in features
// (64 cols per chunk so LDS stays under 64KB). bufQ is wave-private.
// ---------------------------------------------------------------------------
template <int FIN, bool STAGE, bool LAST>
__device__ __forceinline__ void outer_layer(
    const half_t* __restrict__ Ag, const half_t* __restrict__ merged_g,
    const half_t* __restrict__ WT, const float* __restrict__ bias,
    half_t* bufP, half_t* bufQ, float* pool,
    int w, int lr, int lk, int t)
{
    f32x4 hacc[2][8] = {};
    constexpr int NCH = FIN / 64;
    #pragma unroll
    for (int ch = 0; ch < NCH; ch++) {
        if constexpr (STAGE) {
            __syncthreads();   // prior chunk's bufP reads complete
            for (int i = t; i < 1024; i += 256) {
                int s = i >> 3, fo = (i & 7) * 8;
                if (s < NPO) {
                    f16x8 hv = *(const f16x8*)&merged_g[(size_t)s * 192 + ch * 64 + fo];
                    #pragma unroll
                    for (int j = 0; j < 8; j++) lds_sth(bufP, fo + j, s, 256, hv[j]);
                } else {
                    #pragma unroll
                    for (int j = 0; j < 8; j++) lds_sth(bufP, fo + j, s, 256, (half_t)0.f);
                }
            }
            __syncthreads();
        }
        const int rowbase = STAGE ? 0 : ch * 64;
        // T chunk = Â @ h_in[:, ch*64:+64]
        f32x4 tacc[2][4] = {};
        #pragma unroll
        for (int ks = 0; ks < 4; ks++) {
            f16x8 a0 = *(const f16x8*)&Ag[(w * 32 + lr) * 128 + ks * 32 + lk * 8];
            f16x8 a1 = *(const f16x8*)&Ag[(w * 32 + 16 + lr) * 128 + ks * 32 + lk * 8];
            #pragma unroll
            for (int nt = 0; nt < 4; nt++) {
                f16x8 b = lds_ldA(bufP, rowbase + nt * 16 + lr, ks * 32 + lk * 8, 256);
                tacc[0][nt] = MFMA(a0, b, tacc[0][nt]);
                tacc[1][nt] = MFMA(a1, b, tacc[1][nt]);
            }
        }
        #pragma unroll
        for (int rt = 0; rt < 2; rt++)
            #pragma unroll
            for (int nt = 0; nt < 4; nt++)
                #pragma unroll
                for (int q = 0; q < 4; q++)
                    lds_st(bufQ, w * 32 + rt * 16 + lk * 4 + q, nt * 16 + lr, 128,
                           tacc[rt][nt][q]);
        // H partial: K-slice [ch*64, ch*64+64) of T @ W
        #pragma unroll
        for (int ks = 0; ks < 2; ks++) {
            f16x8 a0 = lds_ldA(bufQ, w * 32 + lr, ks * 32 + lk * 8, 128);
            f16x8 a1 = lds_ldA(bufQ, w * 32 + 16 + lr, ks * 32 + lk * 8, 128);
            #pragma unroll
            for (int nt = 0; nt < 8; nt++) {
                f16x8 b = *(const f16x8*)&WT[(nt * 16 + lr) * FIN + ch * 64 + ks * 32 + lk * 8];
                hacc[0][nt] = MFMA(a0, b, hacc[0][nt]);
                hacc[1][nt] = MFMA(a1, b, hacc[1][nt]);
            }
        }
    }
    __syncthreads();   // all bufP reads complete before overwrite
    if constexpr (!LAST) {
        #pragma unroll
        for (int nt = 0; nt < 8; nt++) {
            int c = nt * 16 + lr;
            float bb = bias[c];
            #pragma unroll
            for (int rt = 0; rt < 2; rt++)
                #pragma unroll
                for (int q = 0; q < 4; q++) {
                    int d = w * 32 + rt * 16 + lk * 4 + q;
                    lds_st(bufP, c, d, 256, fmaxf(hacc[rt][nt][q] + bb, 0.f));
                }
        }
        __syncthreads();
    } else {
        #pragma unroll
        for (int nt = 0; nt < 8; nt++) {
            int c = nt * 16 + lr;
            float bb = bias[c];
            float ps = 0.f;
            #pragma unroll
            for (int rt = 0; rt < 2; rt++)
                #pragma unroll
                for (int q = 0; q < 4; q++) {
                    int d = w * 32 + rt * 16 + lk * 4 + q;
                    float v = fmaxf(hacc[rt][nt][q] + bb, 0.f);
                    ps += (d < NPO) ? v : 0.f;
                }
            ps += __shfl_xor(ps, 16);
            ps += __shfl_xor(ps, 32);
            if (lk == 0) atomicAdd(&pool[c], ps);
        }
        __syncthreads();
    }
}

__global__ __launch_bounds__(256) void k_outer_fused(
    const half_t* __restrict__ Aout, const half_t* __restrict__ merged,
    const half_t* __restrict__ WT3, const float* __restrict__ b3,
    const half_t* __restrict__ WT4, const float* __restrict__ b4,
    const half_t* __restrict__ WT5, const float* __restrict__ b5,
    const half_t* __restrict__ WT6, const float* __restrict__ b6,
    const float* __restrict__ Wc, const float* __restrict__ bc,
    float* __restrict__ out)
{
    __shared__ alignas(16) char smem[49664];
    half_t* bufP = (half_t*)smem;            // [128][128] swz stride 256B
    half_t* bufQ = (half_t*)(smem + 32768);  // [128][64] swz stride 128B
    float*  pool = (float*)(smem + 49152);   // [128]

    const int g = blockIdx.x, t = threadIdx.x;
    const int w = t >> 6, l = t & 63, lr = l & 15, lk = l >> 4;
    const half_t* Ag = Aout + (size_t)g * 16384;
    const half_t* mg = merged + (size_t)g * NPO * 192;

    if (t < 128) pool[t] = 0.f;
    __syncthreads();

    outer_layer<192, true,  false>(Ag, mg, WT3, b3, bufP, bufQ, pool, w, lr, lk, t);
    outer_layer<128, false, false>(Ag, nullptr, WT4, b4, bufP, bufQ, pool, w, lr, lk, t);
    outer_layer<128, false, false>(Ag, nullptr, WT5, b5, bufP, bufQ, pool, w, lr, lk, t);
    outer_layer<128, false, true >(Ag, nullptr, WT6, b6, bufP, bufQ, pool, w, lr, lk, t);

    if (t < NC) {
        float acc = bc[t];
        for (int k = 0; k < 128; k++)
            acc = fmaf(pool[k] * (1.f / NPO), Wc[k * NC + t], acc);
        out[g * NC + t] = acc;
    }
}

extern "C" void kernel_launch(void* const* d_in, const int* in_sizes, int n_in,
                              void* d_out, int out_size, void* d_ws, size_t ws_size,
                              hipStream_t stream)
{
    const float* X       = (const float*)d_in[0];
    const float* outfeat = (const float*)d_in[1];
    const float* iew     = (const float*)d_in[2];
    const float* oew     = (const float*)d_in[3];
    const float* W1 = (const float*)d_in[4];  const float* b1 = (const float*)d_in[5];
    const float* W2 = (const float*)d_in[6];  const float* b2 = (const float*)d_in[7];
    const float* W3 = (const float*)d_in[8];  const float* b3 = (const float*)d_in[9];
    const float* W4 = (const float*)d_in[10]; const float* b4 = (const float*)d_in[11];
    const float* W5 = (const float*)d_in[12]; const float* b5 = (const float*)d_in[13];
    const float* W6 = (const float*)d_in[14]; const float* b6 = (const float*)d_in[15];
    const float* Wc = (const float*)d_in[16]; const float* bc = (const float*)d_in[17];
    const int* isrc = (const int*)d_in[18];   const int* idst = (const int*)d_in[19];
    const int* osrc = (const int*)d_in[20];   const int* odst = (const int*)d_in[21];

    char* base = (char*)d_ws;
    half_t* WT1 = (half_t*)(base + 0);        // [128][64]
    half_t* WT2 = (half_t*)(base + 16384);    // [128][128]
    half_t* WT3 = (half_t*)(base + 49152);    // [128][192]
    half_t* WT4 = (half_t*)(base + 98304);    // [128][128]
    half_t* WT5 = (half_t*)(base + 131072);   // [128][128]
    half_t* WT6 = (half_t*)(base + 163840);   // [128][128]
    half_t* AoutG  = (half_t*)(base + 196608);   // [16][128][128]
    half_t* merged = (half_t*)(base + 720896);   // [2000][192]

    k_prep<<<384, 256, 0, stream>>>(W1, W2, W3, W4, W5, W6, WT1, WT2, WT3, WT4, WT5, WT6);
    k_adj_out<<<NB, 256, 0, stream>>>(oew, osrc, odst, AoutG);
    k_inner_fused<<<N_OUT, 256, 0, stream>>>(X, outfeat, iew, isrc, idst,
                                             WT1, b1, WT2, b2, merged);
    k_outer_fused<<<NB, 256, 0, stream>>>(AoutG, merged, WT3, b3, WT4, b4,
                                          WT5, b5, WT6, b6, Wc, bc, (float*)d_out);
}

// Round 4
// 125.789 us; speedup vs baseline: 11.9085x; 1.1268x over previous
//
#include <hip/hip_runtime.h>

#define NPI 50      // nodes per inner graph
#define EPI 400     // edges per inner graph
#define NPO 125     // nodes per outer graph
#define EPO 1000    // edges per outer graph
#define N_IN 100000
#define N_OUT 2000
#define NB 16       // batch graphs
#define NC 10

typedef _Float16 half_t;
typedef _Float16 f16x8 __attribute__((ext_vector_type(8)));
typedef float f32x4 __attribute__((ext_vector_type(4)));

#define MFMA(a, b, c) __builtin_amdgcn_mfma_f32_16x16x32_f16(a, b, c, 0, 0, 0)

// Swizzled LDS helpers, row-major f16 tiles. XOR of (row&7) into byte bits 4..6
// keeps ds_read_b128 conflict-free when 16 lanes read 16 consecutive rows.
__device__ __forceinline__ f16x8 lds_ld8(const half_t* base, int row, int k, int strideB) {
    return *(const f16x8*)((const char*)base + row * strideB + ((k * 2) ^ ((row & 7) << 4)));
}
__device__ __forceinline__ void lds_st1(half_t* base, int row, int col, int strideB, float v) {
    *(half_t*)((char*)base + row * strideB + ((col * 2) ^ ((row & 7) << 4))) = (half_t)v;
}
__device__ __forceinline__ void lds_st1h(half_t* base, int row, int col, int strideB, half_t v) {
    *(half_t*)((char*)base + row * strideB + ((col * 2) ^ ((row & 7) << 4))) = v;
}
__device__ __forceinline__ void lds_st8(half_t* base, int row, int k, int strideB, f16x8 v) {
    *(f16x8*)((char*)base + row * strideB + ((k * 2) ^ ((row & 7) << 4))) = v;
}
// per-wave scratch [16][32] f16, stride 64B, XOR (row&3)<<4
__device__ __forceinline__ f16x8 scr_ld8(const half_t* base, int row, int k) {
    return *(const f16x8*)((const char*)base + row * 64 + ((k * 2) ^ ((row & 3) << 4)));
}
__device__ __forceinline__ void scr_st1(half_t* base, int row, int col, float v) {
    *(half_t*)((char*)base + row * 64 + ((col * 2) ^ ((row & 3) << 4))) = (half_t)v;
}

// ---------------------------------------------------------------------------
// k_pre: blocks 0..383 convert W1..W6 -> transposed f16; blocks 384..399 build
// dense outer adjacency Â_outer [16][128][128] f16 (row-major, unswizzled).
// ---------------------------------------------------------------------------
__global__ __launch_bounds__(256) void k_pre(
    const float* __restrict__ W1, const float* __restrict__ W2,
    const float* __restrict__ W3, const float* __restrict__ W4,
    const float* __restrict__ W5, const float* __restrict__ W6,
    half_t* __restrict__ WT1, half_t* __restrict__ WT2,
    half_t* __restrict__ WT3, half_t* __restrict__ WT4,
    half_t* __restrict__ WT5, half_t* __restrict__ WT6,
    const float* __restrict__ ew, const int* __restrict__ esrc,
    const int* __restrict__ edst, half_t* __restrict__ Aout)
{
    __shared__ float Af[NPO * NPO];
    __shared__ int cO[NPO], cI[NPO];
    __shared__ float rso[NPO], rsi[NPO];
    const int t = threadIdx.x;

    if (blockIdx.x < 384) {
        int i = blockIdx.x * 256 + t;
        const float* src; half_t* dst; int K;
        if      (i < 8192)  { src = W1; dst = WT1; K = 64; }
        else if (i < 24576) { src = W2; dst = WT2; K = 128; i -= 8192; }
        else if (i < 49152) { src = W3; dst = WT3; K = 192; i -= 24576; }
        else if (i < 65536) { src = W4; dst = WT4; K = 128; i -= 49152; }
        else if (i < 81920) { src = W5; dst = WT5; K = 128; i -= 65536; }
        else                { src = W6; dst = WT6; K = 128; i -= 81920; }
        int c = i & 127, k = i >> 7;
        dst[c * K + k] = (half_t)src[k * 128 + c];
        return;
    }

    const int g = blockIdx.x - 384;
    const int nb = g * NPO, eb = g * EPO;
    for (int i = t; i < NPO * NPO; i += 256) Af[i] = 0.f;
    if (t < NPO) { cO[t] = 0; cI[t] = 0; }
    __syncthreads();
    for (int e = t; e < EPO; e += 256) {
        int s = esrc[eb + e] - nb, d = edst[eb + e] - nb;
        atomicAdd(&Af[d * NPO + s], ew[eb + e]);
        atomicAdd(&cO[s], 1); atomicAdd(&cI[d], 1);
    }
    __syncthreads();
    if (t < NPO) {
        rso[t] = rsqrtf((float)max(cO[t], 1));
        rsi[t] = rsqrtf((float)max(cI[t], 1));
    }
    __syncthreads();
    for (int i = t; i < 128 * 16; i += 256) {
        int d = i >> 4, s0 = (i & 15) * 8;
        f16x8 v;
        #pragma unroll
        for (int j = 0; j < 8; j++) {
            int s = s0 + j;
            float x = (d < NPO && s < NPO) ? Af[d * NPO + s] * rsi[d] * rso[s] : 0.f;
            v[j] = (half_t)x;
        }
        *(f16x8*)&Aout[(size_t)g * 16384 + d * 128 + s0] = v;
    }
}

// ---------------------------------------------------------------------------
// Inner fused, low-LDS (29.7KB -> 5 blocks/CU). Strip-fused T-stages: T-tile
// MFMA output goes through 1KB/wave scratch straight into the H-GEMM.
// ---------------------------------------------------------------------------
__global__ __launch_bounds__(256, 5) void k_inner(
    const float* __restrict__ X, const float* __restrict__ outfeat,
    const float* __restrict__ ew, const int* __restrict__ esrc,
    const int* __restrict__ edst,
    const half_t* __restrict__ WT1, const float* __restrict__ b1,
    const half_t* __restrict__ WT2, const float* __restrict__ b2,
    half_t* __restrict__ merged)
{
    __shared__ alignas(16) char smem[29696];
    half_t* Ah  = (half_t*)smem;             // [64][64] swz s128, 8KB
    half_t* R2  = (half_t*)(smem + 8192);    // XT [64][64] s128 then h1T [128][64] s128
    float*  Af  = (float*)(smem + 8192);     // [64][64] f32 (alias of R2)
    half_t* scr = (half_t*)(smem + 24576);   // [4 waves][16][32] f16
    float*  pool= (float*)(smem + 28672);    // [128]
    int*    cO  = (int*)(smem + 29184);      // [64]
    int*    cI  = (int*)(smem + 29440);      // [64]

    const int g = blockIdx.x, t = threadIdx.x;
    const int w = t >> 6, l = t & 63, lr = l & 15, lk = l >> 4;
    const int nb = g * NPI, eb = g * EPI;
    half_t* scrw = scr + w * 512;

    // prefetches (in flight across the zero-init)
    float ofv = (t < 64) ? outfeat[(size_t)g * 64 + t] : 0.f;
    int s0e, d0e; float w0e;
    { int e = eb + t; s0e = esrc[e] - nb; d0e = edst[e] - nb; w0e = ew[e]; }
    int s1e = 0, d1e = 0; float w1e = 0.f;
    const bool e1v = (t + 256 < EPI);
    if (e1v) { int e = eb + t + 256; s1e = esrc[e] - nb; d1e = edst[e] - nb; w1e = ew[e]; }

    if (t < 64) { cO[t] = 0; cI[t] = 0; }
    if (t >= 64 && t < 192) pool[t - 64] = 0.f;
    for (int i = t; i < 4096; i += 256) Af[i] = 0.f;
    __syncthreads();                                         // B1

    atomicAdd(&Af[d0e * 64 + s0e], w0e);
    atomicAdd(&cO[s0e], 1); atomicAdd(&cI[d0e], 1);
    if (e1v) {
        atomicAdd(&Af[d1e * 64 + s1e], w1e);
        atomicAdd(&cO[s1e], 1); atomicAdd(&cI[d1e], 1);
    }
    __syncthreads();                                         // B2

    // X prefetch (coalesced: 4 lanes per row) — overlaps the convert loop
    const int srow = t >> 2, qc = t & 3;
    float4 xr0 = {0,0,0,0}, xr1 = xr0, xr2 = xr0, xr3 = xr0;
    if (srow < NPI) {
        const float* xp = &X[(size_t)(nb + srow) * 64 + qc * 16];
        xr0 = *(const float4*)(xp + 0);
        xr1 = *(const float4*)(xp + 4);
        xr2 = *(const float4*)(xp + 8);
        xr3 = *(const float4*)(xp + 12);
    }

    // Â = rsi[d] * Af * rso[s] -> f16 swizzled (rows/cols >=50 are zero)
    for (int i = t; i < 4096; i += 256) {
        int d = i >> 6, s = i & 63;
        float v = Af[i] * rsqrtf((float)max(cI[d], 1)) * rsqrtf((float)max(cO[s], 1));
        lds_st1(Ah, d, s, 128, v);
    }
    __syncthreads();                                         // B3 (Af reads done)

    // XT[f][s] (overwrites Af region)
    {
        float xv[16] = {xr0.x,xr0.y,xr0.z,xr0.w, xr1.x,xr1.y,xr1.z,xr1.w,
                        xr2.x,xr2.y,xr2.z,xr2.w, xr3.x,xr3.y,xr3.z,xr3.w};
        #pragma unroll
        for (int i = 0; i < 16; i++) lds_st1(R2, qc * 16 + i, srow, 128, xv[i]);
    }
    __syncthreads();                                         // B4

    // ---- T1 = Â@X (strip-fused) -> H1 = relu(T1@W1+b1), wave = 16 rows ----
    f32x4 hacc[8] = {};
    #pragma unroll
    for (int kf = 0; kf < 2; kf++) {
        #pragma unroll
        for (int j = 0; j < 2; j++) {
            const int ft = kf * 2 + j;
            f32x4 tacc = {};
            #pragma unroll
            for (int ks = 0; ks < 2; ks++) {
                f16x8 a = lds_ld8(Ah, w * 16 + lr, ks * 32 + lk * 8, 128);
                f16x8 b = lds_ld8(R2, ft * 16 + lr, ks * 32 + lk * 8, 128);
                tacc = MFMA(a, b, tacc);
            }
            #pragma unroll
            for (int q = 0; q < 4; q++) scr_st1(scrw, lk * 4 + q, j * 16 + lr, tacc[q]);
        }
        f16x8 a1 = scr_ld8(scrw, lr, lk * 8);
        #pragma unroll
        for (int nt = 0; nt < 8; nt++) {
            f16x8 b = *(const f16x8*)&WT1[(nt * 16 + lr) * 64 + kf * 32 + lk * 8];
            hacc[nt] = MFMA(a1, b, hacc[nt]);
        }
    }
    __syncthreads();                                         // B5 (XT reads done)
    #pragma unroll
    for (int nt = 0; nt < 8; nt++) {
        int c = nt * 16 + lr;
        float bb = b1[c];
        #pragma unroll
        for (int q = 0; q < 4; q++)
            lds_st1(R2, c, w * 16 + lk * 4 + q, 128, fmaxf(hacc[nt][q] + bb, 0.f));
    }
    __syncthreads();                                         // B6

    // ---- T2 = Â@h1 (strip-fused) -> H2 = relu(T2@W2+b2) -> masked pool ----
    f32x4 h2[8] = {};
    #pragma unroll
    for (int kf = 0; kf < 4; kf++) {
        #pragma unroll
        for (int j = 0; j < 2; j++) {
            const int ft = kf * 2 + j;
            f32x4 tacc = {};
            #pragma unroll
            for (int ks = 0; ks < 2; ks++) {
                f16x8 a = lds_ld8(Ah, w * 16 + lr, ks * 32 + lk * 8, 128);
                f16x8 b = lds_ld8(R2, ft * 16 + lr, ks * 32 + lk * 8, 128);
                tacc = MFMA(a, b, tacc);
            }
            #pragma unroll
            for (int q = 0; q < 4; q++) scr_st1(scrw, lk * 4 + q, j * 16 + lr, tacc[q]);
        }
        f16x8 a1 = scr_ld8(scrw, lr, lk * 8);
        #pragma unroll
        for (int nt = 0; nt < 8; nt++) {
            f16x8 b = *(const f16x8*)&WT2[(nt * 16 + lr) * 128 + kf * 32 + lk * 8];
            h2[nt] = MFMA(a1, b, h2[nt]);
        }
    }
    #pragma unroll
    for (int nt = 0; nt < 8; nt++) {
        int c = nt * 16 + lr;
        float bb = b2[c];
        float ps = 0.f;
        #pragma unroll
        for (int q = 0; q < 4; q++) {
            int m = w * 16 + lk * 4 + q;
            float v = fmaxf(h2[nt][q] + bb, 0.f);
            ps += (m < NPI) ? v : 0.f;
        }
        ps += __shfl_xor(ps, 16);
        ps += __shfl_xor(ps, 32);
        if (lk == 0) atomicAdd(&pool[c], ps);
    }
    __syncthreads();                                         // B7
    if (t < 64) merged[(size_t)g * 192 + t] = (half_t)ofv;
    else if (t < 192) merged[(size_t)g * 192 + t] = (half_t)(pool[t - 64] * (1.f / NPI));
}

// ---------------------------------------------------------------------------
// Outer fused: 512 threads (8 waves x 16 rows). Â staged in LDS once.
// ---------------------------------------------------------------------------
template <int FIN, bool STAGE, bool LAST>
__device__ __forceinline__ void outer_layer(
    const half_t* AgL, const half_t* __restrict__ mg,
    const half_t* __restrict__ WT, const float* __restrict__ bias,
    half_t* bufP, half_t* bufQ, float* pool,
    int w, int lr, int lk, int t)
{
    f32x4 hacc[8] = {};
    constexpr int NCH = FIN / 64;
    #pragma unroll
    for (int ch = 0; ch < NCH; ch++) {
        if constexpr (STAGE) {
            __syncthreads();
            for (int i = t; i < 1024; i += 512) {
                int s = i >> 3, fo = (i & 7) * 8;
                f16x8 hv = {};
                if (s < NPO) hv = *(const f16x8*)&mg[(size_t)s * 192 + ch * 64 + fo];
                #pragma unroll
                for (int j = 0; j < 8; j++) lds_st1h(bufP, fo + j, s, 256, hv[j]);
            }
            __syncthreads();
        }
        const int rb = STAGE ? 0 : ch * 64;
        // T chunk = Â @ h[:, ch*64:+64]
        f32x4 tacc[4] = {};
        #pragma unroll
        for (int ks = 0; ks < 4; ks++) {
            f16x8 a = lds_ld8(AgL, w * 16 + lr, ks * 32 + lk * 8, 256);
            #pragma unroll
            for (int nt = 0; nt < 4; nt++) {
                f16x8 b = lds_ld8(bufP, rb + nt * 16 + lr, ks * 32 + lk * 8, 256);
                tacc[nt] = MFMA(a, b, tacc[nt]);
            }
        }
        #pragma unroll
        for (int nt = 0; nt < 4; nt++)
            #pragma unroll
            for (int q = 0; q < 4; q++)
                lds_st1(bufQ, w * 16 + lk * 4 + q, nt * 16 + lr, 128, tacc[nt][q]);
        // wave-private rows: no barrier
        #pragma unroll
        for (int ks2 = 0; ks2 < 2; ks2++) {
            f16x8 a1 = lds_ld8(bufQ, w * 16 + lr, ks2 * 32 + lk * 8, 128);
            #pragma unroll
            for (int nt = 0; nt < 8; nt++) {
                f16x8 b = *(const f16x8*)&WT[(nt * 16 + lr) * FIN + ch * 64 + ks2 * 32 + lk * 8];
                hacc[nt] = MFMA(a1, b, hacc[nt]);
            }
        }
    }
    __syncthreads();
    if constexpr (!LAST) {
        #pragma unroll
        for (int nt = 0; nt < 8; nt++) {
            int c = nt * 16 + lr;
            float bb = bias[c];
            #pragma unroll
            for (int q = 0; q < 4; q++)
                lds_st1(bufP, c, w * 16 + lk * 4 + q, 256, fmaxf(hacc[nt][q] + bb, 0.f));
        }
        __syncthreads();
    } else {
        #pragma unroll
        for (int nt = 0; nt < 8; nt++) {
            int c = nt * 16 + lr;
            float bb = bias[c];
            float ps = 0.f;
            #pragma unroll
            for (int q = 0; q < 4; q++) {
                int d = w * 16 + lk * 4 + q;
                float v = fmaxf(hacc[nt][q] + bb, 0.f);
                ps += (d < NPO) ? v : 0.f;
            }
            ps += __shfl_xor(ps, 16);
            ps += __shfl_xor(ps, 32);
            if (lk == 0) atomicAdd(&pool[c], ps);
        }
        __syncthreads();
    }
}

__global__ __launch_bounds__(512) void k_outer(
    const half_t* __restrict__ Aout, const half_t* __restrict__ merged,
    const half_t* __restrict__ WT3, const float* __restrict__ b3,
    const half_t* __restrict__ WT4, const float* __restrict__ b4,
    const half_t* __restrict__ WT5, const float* __restrict__ b5,
    const half_t* __restrict__ WT6, const float* __restrict__ b6,
    const float* __restrict__ Wc, const float* __restrict__ bc,
    float* __restrict__ out)
{
    __shared__ alignas(16) char smem[82432];
    half_t* AgL  = (half_t*)smem;             // [128][128] swz s256
    half_t* bufP = (half_t*)(smem + 32768);   // [128][128] swz s256 (h^T)
    half_t* bufQ = (half_t*)(smem + 65536);   // [128][64] swz s128 (T)
    float*  pool = (float*)(smem + 81920);    // [128]

    const int g = blockIdx.x, t = threadIdx.x;
    const int w = t >> 6, l = t & 63, lr = l & 15, lk = l >> 4;
    const half_t* mg = merged + (size_t)g * NPO * 192;

    for (int i = t; i < 2048; i += 512) {
        int row = i >> 4, k0 = (i & 15) * 8;
        f16x8 v = *(const f16x8*)&Aout[(size_t)g * 16384 + row * 128 + k0];
        lds_st8(AgL, row, k0, 256, v);
    }
    if (t < 128) pool[t] = 0.f;
    __syncthreads();

    outer_layer<192, true,  false>(AgL, mg, WT3, b3, bufP, bufQ, pool, w, lr, lk, t);
    outer_layer<128, false, false>(AgL, nullptr, WT4, b4, bufP, bufQ, pool, w, lr, lk, t);
    outer_layer<128, false, false>(AgL, nullptr, WT5, b5, bufP, bufQ, pool, w, lr, lk, t);
    outer_layer<128, false, true >(AgL, nullptr, WT6, b6, bufP, bufQ, pool, w, lr, lk, t);

    if (t < NC) {
        float acc = bc[t];
        for (int k = 0; k < 128; k++)
            acc = fmaf(pool[k] * (1.f / NPO), Wc[k * NC + t], acc);
        out[g * NC + t] = acc;
    }
}

extern "C" void kernel_launch(void* const* d_in, const int* in_sizes, int n_in,
                              void* d_out, int out_size, void* d_ws, size_t ws_size,
                              hipStream_t stream)
{
    const float* X       = (const float*)d_in[0];
    const float* outfeat = (const float*)d_in[1];
    const float* iew     = (const float*)d_in[2];
    const float* oew     = (const float*)d_in[3];
    const float* W1 = (const float*)d_in[4];  const float* b1 = (const float*)d_in[5];
    const float* W2 = (const float*)d_in[6];  const float* b2 = (const float*)d_in[7];
    const float* W3 = (const float*)d_in[8];  const float* b3 = (const float*)d_in[9];
    const float* W4 = (const float*)d_in[10]; const float* b4 = (const float*)d_in[11];
    const float* W5 = (const float*)d_in[12]; const float* b5 = (const float*)d_in[13];
    const float* W6 = (const float*)d_in[14]; const float* b6 = (const float*)d_in[15];
    const float* Wc = (const float*)d_in[16]; const float* bc = (const float*)d_in[17];
    const int* isrc = (const int*)d_in[18];   const int* idst = (const int*)d_in[19];
    const int* osrc = (const int*)d_in[20];   const int* odst = (const int*)d_in[21];

    char* base = (char*)d_ws;
    half_t* WT1 = (half_t*)(base + 0);        // [128][64]
    half_t* WT2 = (half_t*)(base + 16384);    // [128][128]
    half_t* WT3 = (half_t*)(base + 49152);    // [128][192]
    half_t* WT4 = (half_t*)(base + 98304);    // [128][128]
    half_t* WT5 = (half_t*)(base + 131072);   // [128][128]
    half_t* WT6 = (half_t*)(base + 163840);   // [128][128]
    half_t* AoutG  = (half_t*)(base + 196608);   // [16][128][128]
    half_t* merged = (half_t*)(base + 720896);   // [2000][192]

    k_pre<<<400, 256, 0, stream>>>(W1, W2, W3, W4, W5, W6,
                                   WT1, WT2, WT3, WT4, WT5, WT6,
                                   oew, osrc, odst, AoutG);
    k_inner<<<N_OUT, 256, 0, stream>>>(X, outfeat, iew, isrc, idst,
                                       WT1, b1, WT2, b2, merged);
    k_outer<<<NB, 512, 0, stream>>>(AoutG, merged, WT3, b3, WT4, b4,
                                    WT5, b5, WT6, b6, Wc, bc, (float*)d_out);
}